// Round 3
// baseline (223.460 us; speedup 1.0000x reference)
//
#include <hip/hip_runtime.h>
#include <hip/hip_bf16.h>
#include <stdint.h>

#define Bsz   16384
#define Tt    79
#define Hh    256
#define Dd    256
#define KP    272    // padded K: 256 h-cols + 3 x rows + 1 bias row + 12 zero pad
#define LROW  280    // LDS row stride in bf16 (560 B): 140 dw == 12 mod 32 -> conflict-free
#define NTILE 32     // batch rows per block (2 blocks/CU for barrier decoupling)
#define THR   256    // 4 waves: wave w = m-quarter, each 64 m-cols x 32 n-rows

typedef __attribute__((ext_vector_type(8)))  short  short8;
typedef __attribute__((ext_vector_type(4)))  float  float4_;
typedef __attribute__((ext_vector_type(16))) float  float16_;

__device__ __forceinline__ unsigned short f2bf(float f){
  unsigned u = __float_as_uint(f);
  u += 0x7fffu + ((u >> 16) & 1u);      // RNE
  return (unsigned short)(u >> 16);
}
__device__ __forceinline__ unsigned pk2(float a, float b){
  // v_cvt_pk_bf16_f32 on gfx950 (RNE), single VALU op
  __hip_bfloat162 h = __float22bfloat162_rn(make_float2(a, b));
  return *(unsigned*)&h;
}

__global__ void build_tables(const float* __restrict__ W_in,
                             const float* __restrict__ U,
                             const float* __restrict__ b_rnn,
                             const float* __restrict__ W_d,
                             const float* __restrict__ b_d,
                             unsigned short* __restrict__ Ut,
                             unsigned short* __restrict__ Wdt){
  const int TBL = 256 * KP;
  int idx = blockIdx.x * 256 + threadIdx.x;
  if (idx >= 2 * TBL) return;
  int tb  = idx / TBL;
  int rem = idx - tb * TBL;
  int m = rem / KP;
  int k = rem - m * KP;
  float v = 0.f;
  if (tb == 0){
    if      (k < 256) v = U[k * 256 + m];
    else if (k < 259) v = W_in[(k - 256) * 256 + m];
    else if (k == 259) v = b_rnn[m];
  } else {
    if      (k < 256) v = W_d[k * 256 + m];
    else if (k == 259) v = b_d[m];
  }
  unsigned short o = f2bf(v);
  if (tb == 0) Ut[rem] = o; else Wdt[rem] = o;
}

// 512 blocks x 256 threads = 2 blocks/CU (two independent barrier domains per
// CU). Each block owns 32 batch rows; h^T (32 x 272 bf16, double-buffered) in
// LDS. Wave w = m-quarter: 64 h-cols = 2 MFMA 32x32 tiles x 32 batch rows.
// A-fragments loop-invariant in regs (136). K-loop software-pipelined in read
// groups (kt 0-8 prefetched, then 4-4 behind the MFMA groups) so ds_read
// latency hides under MFMA issue; acc single-chain per mt (round-2 showed the
// chain split is not the limiter) to keep peak pressure ~230 < 256.
__global__ __launch_bounds__(THR, 2) void rnn_main(
    const float* __restrict__ x0,
    const float* __restrict__ x1,
    const float* __restrict__ x2,
    const unsigned short* __restrict__ Ut,
    const unsigned short* __restrict__ Wdt,
    float* __restrict__ out){
  __shared__ __align__(16) short hbuf[2][NTILE * LROW];

  const int tid  = threadIdx.x;
  const int lane = tid & 63;
  const int wm   = tid >> 6;        // m-quarter 0..3
  const int nrow = lane & 31;       // B operand / C col: batch row
  const int hi   = lane >> 5;       // k-half for A/B fragments
  const int hi8  = hi * 8;
  const int hi4  = hi * 4;
  const int bbase = blockIdx.x * NTILE;

  // ---- zero both LDS buffers (h0 = 0, pad rows = 0) ----
  {
    int4* p = (int4*)&hbuf[0][0];
    const int tot = 2 * NTILE * LROW * 2 / 16;
    int4 z = make_int4(0, 0, 0, 0);
    for (int i = tid; i < tot; i += THR) p[i] = z;
  }
  __syncthreads();

  // bias row (k=259) = 1.0 bf16 in BOTH buffers (never overwritten)
  if (tid < NTILE){
    hbuf[0][tid * LROW + 259] = (short)0x3F80;
    hbuf[1][tid * LROW + 259] = (short)0x3F80;
  }

  // x rows for step t=0 (original time index T-1) into buf 0
  const bool stager = (wm == 0) && (lane < NTILE);
  const int  sn  = lane & (NTILE - 1);
  const int  sgb = bbase + sn;
  if (stager){
    int tr = Tt - 1;
    float a = x0[sgb * Tt + tr];
    float b = x1[sgb * Tt + tr];
    float c = x2[sgb * Tt + tr];
    *(unsigned*)&hbuf[0][sn * LROW + 256] = pk2(a, b);
    hbuf[0][sn * LROW + 258] = (short)f2bf(c);
  }

  // ---- preload A fragments: 2 mt x 17 kt = 34 short8 (136 regs) ----
  short8 afr[2][17];
  #pragma unroll
  for (int mt = 0; mt < 2; ++mt){
    const unsigned short* p = Ut + (wm * 64 + mt * 32 + nrow) * KP + hi8;
    #pragma unroll
    for (int kt = 0; kt < 17; ++kt){
      afr[mt][kt] = *(const short8*)(p + kt * 16);
    }
  }

  __syncthreads();

  const float16_ zz = {0.f,0.f,0.f,0.f,0.f,0.f,0.f,0.f,
                       0.f,0.f,0.f,0.f,0.f,0.f,0.f,0.f};
  float16_ acc[2];

  // ---- 79 recurrence steps, ONE barrier each (double-buffered h) ----
  #pragma unroll 1
  for (int t = 0; t < Tt; ++t){
    // prefetch x for step t+1 (latency hidden under the K-loop)
    float xa = 0.f, xb = 0.f, xc = 0.f;
    if (stager && t < Tt - 1){
      int tr = Tt - 2 - t;
      xa = x0[sgb * Tt + tr];
      xb = x1[sgb * Tt + tr];
      xc = x2[sgb * Tt + tr];
    }

    const short* hb = &hbuf[t & 1][0];
    short*       hw = &hbuf[(t + 1) & 1][0];
    const short* rbase = &hb[nrow * LROW + hi8];

    __builtin_amdgcn_s_setprio(1);
    short8 bb[17];
    // read group 0+1: kt 0..8 issued before any MFMA (36-reg window)
    #pragma unroll
    for (int kt = 0; kt < 9; ++kt)
      bb[kt] = *(const short8*)(rbase + kt * 16);
    // MFMA kt 0..4 (reads for 0..8 in flight / landed)
    #pragma unroll
    for (int kt = 0; kt < 5; ++kt){
      if (kt == 0){
        acc[0] = __builtin_amdgcn_mfma_f32_32x32x16_bf16(afr[0][0], bb[0], zz, 0, 0, 0);
        acc[1] = __builtin_amdgcn_mfma_f32_32x32x16_bf16(afr[1][0], bb[0], zz, 0, 0, 0);
      } else {
        acc[0] = __builtin_amdgcn_mfma_f32_32x32x16_bf16(afr[0][kt], bb[kt], acc[0], 0, 0, 0);
        acc[1] = __builtin_amdgcn_mfma_f32_32x32x16_bf16(afr[1][kt], bb[kt], acc[1], 0, 0, 0);
      }
    }
    // read group 2: kt 9..12 (hides under MFMA kt 5..8)
    #pragma unroll
    for (int kt = 9; kt < 13; ++kt)
      bb[kt] = *(const short8*)(rbase + kt * 16);
    #pragma unroll
    for (int kt = 5; kt < 9; ++kt){
      acc[0] = __builtin_amdgcn_mfma_f32_32x32x16_bf16(afr[0][kt], bb[kt], acc[0], 0, 0, 0);
      acc[1] = __builtin_amdgcn_mfma_f32_32x32x16_bf16(afr[1][kt], bb[kt], acc[1], 0, 0, 0);
    }
    // read group 3: kt 13..16 (hides under MFMA kt 9..12)
    #pragma unroll
    for (int kt = 13; kt < 17; ++kt)
      bb[kt] = *(const short8*)(rbase + kt * 16);
    #pragma unroll
    for (int kt = 9; kt < 17; ++kt){
      acc[0] = __builtin_amdgcn_mfma_f32_32x32x16_bf16(afr[0][kt], bb[kt], acc[0], 0, 0, 0);
      acc[1] = __builtin_amdgcn_mfma_f32_32x32x16_bf16(afr[1][kt], bb[kt], acc[1], 0, 0, 0);
    }
    __builtin_amdgcn_s_setprio(0);

    // relu + pack (v_cvt_pk_bf16_f32), write h(t+1) into the OTHER buffer.
    // C/D 32x32 layout: col=lane&31 (=nrow), row m = 8*q + 4*hi + (reg&3)
    #pragma unroll
    for (int mt = 0; mt < 2; ++mt){
      #pragma unroll
      for (int q = 0; q < 4; ++q){
        uint2 w;
        w.x = pk2(fmaxf(acc[mt][4*q+0], 0.f), fmaxf(acc[mt][4*q+1], 0.f));
        w.y = pk2(fmaxf(acc[mt][4*q+2], 0.f), fmaxf(acc[mt][4*q+3], 0.f));
        *(uint2*)&hw[nrow * LROW + wm * 64 + mt * 32 + 8 * q + hi4] = w;
      }
    }
    if (stager && t < Tt - 1){
      *(unsigned*)&hw[sn * LROW + 256] = pk2(xa, xb);
      hw[sn * LROW + 258] = (short)f2bf(xc);
    }

    __syncthreads();   // h(t+1)/x(t+1) visible; next step reads other buffer
  }

  // ---- epilogue: out^T = W_d^T h^T + b_d; final h is in buf[Tt&1] = buf[1] ----
  // (x rows in final buffer are stale but Wdt rows 256-258 are zero; bias row
  //  k=259 is 1.0 and Wdt[.,259] = b_d.)
  const short* hb = &hbuf[Tt & 1][0];
  float16_ oacc[2];
  #pragma unroll
  for (int kt = 0; kt < 17; ++kt){
    short8 b  = *(const short8*)&hb[nrow * LROW + kt * 16 + hi8];
    short8 w0 = *(const short8*)(Wdt + (wm * 64 +  0 + nrow) * KP + kt * 16 + hi8);
    short8 w1 = *(const short8*)(Wdt + (wm * 64 + 32 + nrow) * KP + kt * 16 + hi8);
    if (kt == 0){
      oacc[0] = __builtin_amdgcn_mfma_f32_32x32x16_bf16(w0, b, zz, 0, 0, 0);
      oacc[1] = __builtin_amdgcn_mfma_f32_32x32x16_bf16(w1, b, zz, 0, 0, 0);
    } else {
      oacc[0] = __builtin_amdgcn_mfma_f32_32x32x16_bf16(w0, b, oacc[0], 0, 0, 0);
      oacc[1] = __builtin_amdgcn_mfma_f32_32x32x16_bf16(w1, b, oacc[1], 0, 0, 0);
    }
  }

  #pragma unroll
  for (int mt = 0; mt < 2; ++mt){
    #pragma unroll
    for (int q = 0; q < 4; ++q){
      float4_ v = {oacc[mt][4*q+0], oacc[mt][4*q+1],
                   oacc[mt][4*q+2], oacc[mt][4*q+3]};
      *(float4_*)&out[(bbase + nrow) * Dd + wm * 64 + mt * 32 + 8 * q + hi4] = v;
    }
  }
}

extern "C" void kernel_launch(void* const* d_in, const int* in_sizes, int n_in,
                              void* d_out, int out_size, void* d_ws, size_t ws_size,
                              hipStream_t stream){
  const float* x0    = (const float*)d_in[0];
  const float* x1    = (const float*)d_in[1];
  const float* x2    = (const float*)d_in[2];
  const float* W_in  = (const float*)d_in[3];
  const float* U     = (const float*)d_in[4];
  const float* b_rnn = (const float*)d_in[5];
  const float* W_d   = (const float*)d_in[6];
  const float* b_d   = (const float*)d_in[7];

  unsigned short* Ut  = (unsigned short*)d_ws;
  unsigned short* Wdt = Ut + 256 * KP;
  float* out = (float*)d_out;

  build_tables<<<(2 * 256 * KP + 255) / 256, 256, 0, stream>>>(W_in, U, b_rnn, W_d, b_d, Ut, Wdt);
  rnn_main<<<Bsz / NTILE, THR, 0, stream>>>(x0, x1, x2, Ut, Wdt, out);
}

// Round 4
// 221.591 us; speedup vs baseline: 1.0084x; 1.0084x over previous
//
#include <hip/hip_runtime.h>
#include <hip/hip_bf16.h>
#include <stdint.h>

#define Bsz   16384
#define Tt    79
#define Hh    256
#define Dd    256
#define KP    272    // padded K: 256 h-cols + 3 x rows + 1 bias row + 12 zero pad
#define LROW  280    // LDS row stride in bf16 (560 B): 140 dw == 12 mod 32 -> conflict-free
#define NTILE 32     // batch rows per block (2 blocks/CU for barrier decoupling)
#define THR   256    // 4 waves: wave w = m-quarter, each 64 m-cols x 32 n-rows

typedef __attribute__((ext_vector_type(8)))  short  short8;
typedef __attribute__((ext_vector_type(4)))  float  float4_;
typedef __attribute__((ext_vector_type(16))) float  float16_;

__device__ __forceinline__ unsigned short f2bf(float f){
  unsigned u = __float_as_uint(f);
  u += 0x7fffu + ((u >> 16) & 1u);      // RNE
  return (unsigned short)(u >> 16);
}
__device__ __forceinline__ unsigned pk2(float a, float b){
  // v_cvt_pk_bf16_f32 on gfx950 (RNE), single VALU op
  __hip_bfloat162 h = __float22bfloat162_rn(make_float2(a, b));
  return *(unsigned*)&h;
}

__global__ void build_tables(const float* __restrict__ W_in,
                             const float* __restrict__ U,
                             const float* __restrict__ b_rnn,
                             const float* __restrict__ W_d,
                             const float* __restrict__ b_d,
                             unsigned short* __restrict__ Ut,
                             unsigned short* __restrict__ Wdt){
  const int TBL = 256 * KP;
  int idx = blockIdx.x * 256 + threadIdx.x;
  if (idx >= 2 * TBL) return;
  int tb  = idx / TBL;
  int rem = idx - tb * TBL;
  int m = rem / KP;
  int k = rem - m * KP;
  float v = 0.f;
  if (tb == 0){
    if      (k < 256) v = U[k * 256 + m];
    else if (k < 259) v = W_in[(k - 256) * 256 + m];
    else if (k == 259) v = b_rnn[m];
  } else {
    if      (k < 256) v = W_d[k * 256 + m];
    else if (k == 259) v = b_d[m];
  }
  unsigned short o = f2bf(v);
  if (tb == 0) Ut[rem] = o; else Wdt[rem] = o;
}

// 512 blocks x 256 threads = 2 blocks/CU. Each block owns 32 batch rows; h^T
// (32 x 272 bf16, double-buffered) in LDS. Wave w = m-quarter: 64 h-cols = 2
// MFMA 32x32 tiles x 32 batch rows. A-fragments loop-invariant in regs.
//
// Round-4 change: ANTI-PHASE STAGGER. Rounds 1-3 showed step time pinned at
// ~4800 cyc with MFMA pipe 2200, DS ~1600, VALU ~1400 barely overlapping:
// the two co-resident blocks phase-lock (symmetric barrier loops + shared-pipe
// contention), so MFMA/DS/VALU phases collide instead of interleaving. Odd
// blocks sleep ~half a step before the t-loop; anti-phase is self-sustaining
// (each block then sees an uncontended pipe and equal step times).
__global__ __launch_bounds__(THR, 2) void rnn_main(
    const float* __restrict__ x0,
    const float* __restrict__ x1,
    const float* __restrict__ x2,
    const unsigned short* __restrict__ Ut,
    const unsigned short* __restrict__ Wdt,
    float* __restrict__ out){
  __shared__ __align__(16) short hbuf[2][NTILE * LROW];

  const int tid  = threadIdx.x;
  const int lane = tid & 63;
  const int wm   = tid >> 6;        // m-quarter 0..3
  const int nrow = lane & 31;       // B operand / C col: batch row
  const int hi   = lane >> 5;       // k-half for A/B fragments
  const int hi8  = hi * 8;
  const int hi4  = hi * 4;
  const int bbase = blockIdx.x * NTILE;

  // ---- zero both LDS buffers (h0 = 0, pad rows = 0) ----
  {
    int4* p = (int4*)&hbuf[0][0];
    const int tot = 2 * NTILE * LROW * 2 / 16;
    int4 z = make_int4(0, 0, 0, 0);
    for (int i = tid; i < tot; i += THR) p[i] = z;
  }
  __syncthreads();

  // bias row (k=259) = 1.0 bf16 in BOTH buffers (never overwritten)
  if (tid < NTILE){
    hbuf[0][tid * LROW + 259] = (short)0x3F80;
    hbuf[1][tid * LROW + 259] = (short)0x3F80;
  }

  // x rows for step t=0 (original time index T-1) into buf 0
  const bool stager = (wm == 0) && (lane < NTILE);
  const int  sn  = lane & (NTILE - 1);
  const int  sgb = bbase + sn;
  if (stager){
    int tr = Tt - 1;
    float a = x0[sgb * Tt + tr];
    float b = x1[sgb * Tt + tr];
    float c = x2[sgb * Tt + tr];
    *(unsigned*)&hbuf[0][sn * LROW + 256] = pk2(a, b);
    hbuf[0][sn * LROW + 258] = (short)f2bf(c);
  }

  // ---- preload A fragments: 2 mt x 17 kt = 34 short8 (136 regs) ----
  short8 afr[2][17];
  #pragma unroll
  for (int mt = 0; mt < 2; ++mt){
    const unsigned short* p = Ut + (wm * 64 + mt * 32 + nrow) * KP + hi8;
    #pragma unroll
    for (int kt = 0; kt < 17; ++kt){
      afr[mt][kt] = *(const short8*)(p + kt * 16);
    }
  }

  __syncthreads();

  // ---- anti-phase stagger: odd blocks start ~half a step late ----
  if (blockIdx.x & 1){
    __builtin_amdgcn_s_sleep(20);   // ~1280 cyc
    __builtin_amdgcn_s_sleep(20);   // ~1280 cyc  (total ~2560 ~ half of 4800)
  }

  const float16_ zz = {0.f,0.f,0.f,0.f,0.f,0.f,0.f,0.f,
                       0.f,0.f,0.f,0.f,0.f,0.f,0.f,0.f};
  float16_ acc[2];

  // ---- 79 recurrence steps, ONE barrier each (double-buffered h) ----
  #pragma unroll 1
  for (int t = 0; t < Tt; ++t){
    // prefetch x for step t+1 (latency hidden under the K-loop)
    float xa = 0.f, xb = 0.f, xc = 0.f;
    if (stager && t < Tt - 1){
      int tr = Tt - 2 - t;
      xa = x0[sgb * Tt + tr];
      xb = x1[sgb * Tt + tr];
      xc = x2[sgb * Tt + tr];
    }

    const short* hb = &hbuf[t & 1][0];
    short*       hw = &hbuf[(t + 1) & 1][0];
    const short* rbase = &hb[nrow * LROW + hi8];

    __builtin_amdgcn_s_setprio(1);
    #pragma unroll
    for (int kt = 0; kt < 17; ++kt){
      short8 b = *(const short8*)(rbase + kt * 16);
      if (kt == 0){
        acc[0] = __builtin_amdgcn_mfma_f32_32x32x16_bf16(afr[0][0], b, zz, 0, 0, 0);
        acc[1] = __builtin_amdgcn_mfma_f32_32x32x16_bf16(afr[1][0], b, zz, 0, 0, 0);
      } else {
        acc[0] = __builtin_amdgcn_mfma_f32_32x32x16_bf16(afr[0][kt], b, acc[0], 0, 0, 0);
        acc[1] = __builtin_amdgcn_mfma_f32_32x32x16_bf16(afr[1][kt], b, acc[1], 0, 0, 0);
      }
    }
    __builtin_amdgcn_s_setprio(0);

    // relu + pack (v_cvt_pk_bf16_f32), write h(t+1) into the OTHER buffer.
    // C/D 32x32 layout: col=lane&31 (=nrow), row m = 8*q + 4*hi + (reg&3)
    #pragma unroll
    for (int mt = 0; mt < 2; ++mt){
      #pragma unroll
      for (int q = 0; q < 4; ++q){
        uint2 w;
        w.x = pk2(fmaxf(acc[mt][4*q+0], 0.f), fmaxf(acc[mt][4*q+1], 0.f));
        w.y = pk2(fmaxf(acc[mt][4*q+2], 0.f), fmaxf(acc[mt][4*q+3], 0.f));
        *(uint2*)&hw[nrow * LROW + wm * 64 + mt * 32 + 8 * q + hi4] = w;
      }
    }
    if (stager && t < Tt - 1){
      *(unsigned*)&hw[sn * LROW + 256] = pk2(xa, xb);
      hw[sn * LROW + 258] = (short)f2bf(xc);
    }

    __syncthreads();   // h(t+1)/x(t+1) visible; next step reads other buffer
  }

  // ---- epilogue: out^T = W_d^T h^T + b_d; final h is in buf[Tt&1] = buf[1] ----
  // (x rows in final buffer are stale but Wdt rows 256-258 are zero; bias row
  //  k=259 is 1.0 and Wdt[.,259] = b_d.)
  const short* hb = &hbuf[Tt & 1][0];
  float16_ oacc[2];
  #pragma unroll
  for (int kt = 0; kt < 17; ++kt){
    short8 b  = *(const short8*)&hb[nrow * LROW + kt * 16 + hi8];
    short8 w0 = *(const short8*)(Wdt + (wm * 64 +  0 + nrow) * KP + kt * 16 + hi8);
    short8 w1 = *(const short8*)(Wdt + (wm * 64 + 32 + nrow) * KP + kt * 16 + hi8);
    if (kt == 0){
      oacc[0] = __builtin_amdgcn_mfma_f32_32x32x16_bf16(w0, b, zz, 0, 0, 0);
      oacc[1] = __builtin_amdgcn_mfma_f32_32x32x16_bf16(w1, b, zz, 0, 0, 0);
    } else {
      oacc[0] = __builtin_amdgcn_mfma_f32_32x32x16_bf16(w0, b, oacc[0], 0, 0, 0);
      oacc[1] = __builtin_amdgcn_mfma_f32_32x32x16_bf16(w1, b, oacc[1], 0, 0, 0);
    }
  }

  #pragma unroll
  for (int mt = 0; mt < 2; ++mt){
    #pragma unroll
    for (int q = 0; q < 4; ++q){
      float4_ v = {oacc[mt][4*q+0], oacc[mt][4*q+1],
                   oacc[mt][4*q+2], oacc[mt][4*q+3]};
      *(float4_*)&out[(bbase + nrow) * Dd + wm * 64 + mt * 32 + 8 * q + hi4] = v;
    }
  }
}

extern "C" void kernel_launch(void* const* d_in, const int* in_sizes, int n_in,
                              void* d_out, int out_size, void* d_ws, size_t ws_size,
                              hipStream_t stream){
  const float* x0    = (const float*)d_in[0];
  const float* x1    = (const float*)d_in[1];
  const float* x2    = (const float*)d_in[2];
  const float* W_in  = (const float*)d_in[3];
  const float* U     = (const float*)d_in[4];
  const float* b_rnn = (const float*)d_in[5];
  const float* W_d   = (const float*)d_in[6];
  const float* b_d   = (const float*)d_in[7];

  unsigned short* Ut  = (unsigned short*)d_ws;
  unsigned short* Wdt = Ut + 256 * KP;
  float* out = (float*)d_out;

  build_tables<<<(2 * 256 * KP + 255) / 256, 256, 0, stream>>>(W_in, U, b_rnn, W_d, b_d, Ut, Wdt);
  rnn_main<<<Bsz / NTILE, THR, 0, stream>>>(x0, x1, x2, Ut, Wdt, out);
}

// Round 5
// 210.393 us; speedup vs baseline: 1.0621x; 1.0532x over previous
//
#include <hip/hip_runtime.h>
#include <hip/hip_bf16.h>
#include <stdint.h>

#define Bsz   16384
#define Tt    79
#define Hh    256
#define Dd    256
#define KP    272    // padded K: 256 h-cols + 3 x rows + 1 bias row + 12 zero pad
#define LROW  280    // LDS row stride in bf16 (560 B): 140 dw == 12 mod 32 -> conflict-free
#define NTILE 32     // batch rows per block (2 blocks/CU for barrier decoupling)
#define THR   256    // 4 waves: wave w = m-quarter, each 64 m-cols x 32 n-rows

typedef __attribute__((ext_vector_type(8)))  short  short8;
typedef __attribute__((ext_vector_type(4)))  float  float4_;
typedef __attribute__((ext_vector_type(16))) float  float16_;

__device__ __forceinline__ unsigned short f2bf(float f){
  unsigned u = __float_as_uint(f);
  u += 0x7fffu + ((u >> 16) & 1u);      // RNE
  return (unsigned short)(u >> 16);
}
// HW packed f32x2 -> bf16x2 (RNE). NOTE: no builtin exists on gfx950 and
// __float22bfloat162_rn may lower to the ~11-VALU software RNE sequence --
// round-4 counters showed ~346 VALU instr/wave/step vs ~50 real, which is
// exactly the pack tail. Non-volatile asm: pure, freely schedulable.
__device__ __forceinline__ unsigned pk2(float a, float b){
  unsigned r;
  asm("v_cvt_pk_bf16_f32 %0, %1, %2" : "=v"(r) : "v"(a), "v"(b));
  return r;
}

__global__ void build_tables(const float* __restrict__ W_in,
                             const float* __restrict__ U,
                             const float* __restrict__ b_rnn,
                             const float* __restrict__ W_d,
                             const float* __restrict__ b_d,
                             unsigned short* __restrict__ Ut,
                             unsigned short* __restrict__ Wdt){
  const int TBL = 256 * KP;
  int idx = blockIdx.x * 256 + threadIdx.x;
  if (idx >= 2 * TBL) return;
  int tb  = idx / TBL;
  int rem = idx - tb * TBL;
  int m = rem / KP;
  int k = rem - m * KP;
  float v = 0.f;
  if (tb == 0){
    if      (k < 256) v = U[k * 256 + m];
    else if (k < 259) v = W_in[(k - 256) * 256 + m];
    else if (k == 259) v = b_rnn[m];
  } else {
    if      (k < 256) v = W_d[k * 256 + m];
    else if (k == 259) v = b_d[m];
  }
  unsigned short o = f2bf(v);
  if (tb == 0) Ut[rem] = o; else Wdt[rem] = o;
}

// 512 blocks x 256 threads = 2 blocks/CU. Each block owns 32 batch rows; h^T
// (32 x 272 bf16, double-buffered) in LDS. Wave w = m-quarter: 64 h-cols = 2
// MFMA 32x32 tiles x 32 batch rows. A-fragments loop-invariant in regs.
//
// Cycle model (round 4): step = 4860 cyc = MFMA 2196 + VALU 1385 + tail ~500
// + conflicts ~270 -- ADDITIVE, not overlapped. The VALU term is 7x the real
// work; round-5 attacks it with HW v_cvt_pk_bf16_f32 (see pk2).
__global__ __launch_bounds__(THR, 2) void rnn_main(
    const float* __restrict__ x0,
    const float* __restrict__ x1,
    const float* __restrict__ x2,
    const unsigned short* __restrict__ Ut,
    const unsigned short* __restrict__ Wdt,
    float* __restrict__ out){
  __shared__ __align__(16) short hbuf[2][NTILE * LROW];

  const int tid  = threadIdx.x;
  const int lane = tid & 63;
  const int wm   = tid >> 6;        // m-quarter 0..3
  const int nrow = lane & 31;       // B operand / C col: batch row
  const int hi   = lane >> 5;       // k-half for A/B fragments
  const int hi8  = hi * 8;
  const int hi4  = hi * 4;
  const int bbase = blockIdx.x * NTILE;

  // ---- zero both LDS buffers (h0 = 0, pad rows = 0) ----
  {
    int4* p = (int4*)&hbuf[0][0];
    const int tot = 2 * NTILE * LROW * 2 / 16;
    int4 z = make_int4(0, 0, 0, 0);
    for (int i = tid; i < tot; i += THR) p[i] = z;
  }
  __syncthreads();

  // bias row (k=259) = 1.0 bf16 in BOTH buffers (never overwritten)
  if (tid < NTILE){
    hbuf[0][tid * LROW + 259] = (short)0x3F80;
    hbuf[1][tid * LROW + 259] = (short)0x3F80;
  }

  // x rows for step t=0 (original time index T-1) into buf 0
  const bool stager = (wm == 0) && (lane < NTILE);
  const int  sn  = lane & (NTILE - 1);
  const int  sgb = bbase + sn;
  if (stager){
    int tr = Tt - 1;
    float a = x0[sgb * Tt + tr];
    float b = x1[sgb * Tt + tr];
    float c = x2[sgb * Tt + tr];
    *(unsigned*)&hbuf[0][sn * LROW + 256] = pk2(a, b);
    hbuf[0][sn * LROW + 258] = (short)f2bf(c);
  }

  // ---- preload A fragments: 2 mt x 17 kt = 34 short8 (136 regs) ----
  short8 afr[2][17];
  #pragma unroll
  for (int mt = 0; mt < 2; ++mt){
    const unsigned short* p = Ut + (wm * 64 + mt * 32 + nrow) * KP + hi8;
    #pragma unroll
    for (int kt = 0; kt < 17; ++kt){
      afr[mt][kt] = *(const short8*)(p + kt * 16);
    }
  }

  __syncthreads();

  const float16_ zz = {0.f,0.f,0.f,0.f,0.f,0.f,0.f,0.f,
                       0.f,0.f,0.f,0.f,0.f,0.f,0.f,0.f};
  float16_ acc[2];

  // ---- 79 recurrence steps, ONE barrier each (double-buffered h) ----
  #pragma unroll 1
  for (int t = 0; t < Tt; ++t){
    // prefetch x for step t+1 (latency hidden under the K-loop)
    float xa = 0.f, xb = 0.f, xc = 0.f;
    if (stager && t < Tt - 1){
      int tr = Tt - 2 - t;
      xa = x0[sgb * Tt + tr];
      xb = x1[sgb * Tt + tr];
      xc = x2[sgb * Tt + tr];
    }

    const short* hb = &hbuf[t & 1][0];
    short*       hw = &hbuf[(t + 1) & 1][0];
    const short* rbase = &hb[nrow * LROW + hi8];

    __builtin_amdgcn_s_setprio(1);
    #pragma unroll
    for (int kt = 0; kt < 17; ++kt){
      short8 b = *(const short8*)(rbase + kt * 16);
      if (kt == 0){
        acc[0] = __builtin_amdgcn_mfma_f32_32x32x16_bf16(afr[0][0], b, zz, 0, 0, 0);
        acc[1] = __builtin_amdgcn_mfma_f32_32x32x16_bf16(afr[1][0], b, zz, 0, 0, 0);
      } else {
        acc[0] = __builtin_amdgcn_mfma_f32_32x32x16_bf16(afr[0][kt], b, acc[0], 0, 0, 0);
        acc[1] = __builtin_amdgcn_mfma_f32_32x32x16_bf16(afr[1][kt], b, acc[1], 0, 0, 0);
      }
    }
    __builtin_amdgcn_s_setprio(0);

    // relu + HW pack, write h(t+1) into the OTHER buffer.
    // C/D 32x32 layout: col=lane&31 (=nrow), row m = 8*q + 4*hi + (reg&3)
    #pragma unroll
    for (int mt = 0; mt < 2; ++mt){
      #pragma unroll
      for (int q = 0; q < 4; ++q){
        uint2 w;
        w.x = pk2(fmaxf(acc[mt][4*q+0], 0.f), fmaxf(acc[mt][4*q+1], 0.f));
        w.y = pk2(fmaxf(acc[mt][4*q+2], 0.f), fmaxf(acc[mt][4*q+3], 0.f));
        *(uint2*)&hw[nrow * LROW + wm * 64 + mt * 32 + 8 * q + hi4] = w;
      }
    }
    if (stager && t < Tt - 1){
      *(unsigned*)&hw[sn * LROW + 256] = pk2(xa, xb);
      hw[sn * LROW + 258] = (short)f2bf(xc);
    }

    __syncthreads();   // h(t+1)/x(t+1) visible; next step reads other buffer
  }

  // ---- epilogue: out^T = W_d^T h^T + b_d; final h is in buf[Tt&1] = buf[1] ----
  // (x rows in final buffer are stale but Wdt rows 256-258 are zero; bias row
  //  k=259 is 1.0 and Wdt[.,259] = b_d.)
  const short* hb = &hbuf[Tt & 1][0];
  float16_ oacc[2];
  #pragma unroll
  for (int kt = 0; kt < 17; ++kt){
    short8 b  = *(const short8*)&hb[nrow * LROW + kt * 16 + hi8];
    short8 w0 = *(const short8*)(Wdt + (wm * 64 +  0 + nrow) * KP + kt * 16 + hi8);
    short8 w1 = *(const short8*)(Wdt + (wm * 64 + 32 + nrow) * KP + kt * 16 + hi8);
    if (kt == 0){
      oacc[0] = __builtin_amdgcn_mfma_f32_32x32x16_bf16(w0, b, zz, 0, 0, 0);
      oacc[1] = __builtin_amdgcn_mfma_f32_32x32x16_bf16(w1, b, zz, 0, 0, 0);
    } else {
      oacc[0] = __builtin_amdgcn_mfma_f32_32x32x16_bf16(w0, b, oacc[0], 0, 0, 0);
      oacc[1] = __builtin_amdgcn_mfma_f32_32x32x16_bf16(w1, b, oacc[1], 0, 0, 0);
    }
  }

  #pragma unroll
  for (int mt = 0; mt < 2; ++mt){
    #pragma unroll
    for (int q = 0; q < 4; ++q){
      float4_ v = {oacc[mt][4*q+0], oacc[mt][4*q+1],
                   oacc[mt][4*q+2], oacc[mt][4*q+3]};
      *(float4_*)&out[(bbase + nrow) * Dd + wm * 64 + mt * 32 + 8 * q + hi4] = v;
    }
  }
}

extern "C" void kernel_launch(void* const* d_in, const int* in_sizes, int n_in,
                              void* d_out, int out_size, void* d_ws, size_t ws_size,
                              hipStream_t stream){
  const float* x0    = (const float*)d_in[0];
  const float* x1    = (const float*)d_in[1];
  const float* x2    = (const float*)d_in[2];
  const float* W_in  = (const float*)d_in[3];
  const float* U     = (const float*)d_in[4];
  const float* b_rnn = (const float*)d_in[5];
  const float* W_d   = (const float*)d_in[6];
  const float* b_d   = (const float*)d_in[7];

  unsigned short* Ut  = (unsigned short*)d_ws;
  unsigned short* Wdt = Ut + 256 * KP;
  float* out = (float*)d_out;

  build_tables<<<(2 * 256 * KP + 255) / 256, 256, 0, stream>>>(W_in, U, b_rnn, W_d, b_d, Ut, Wdt);
  rnn_main<<<Bsz / NTILE, THR, 0, stream>>>(x0, x1, x2, Ut, Wdt, out);
}